// Round 3
// baseline (279.772 us; speedup 1.0000x reference)
//
#include <hip/hip_runtime.h>

typedef __bf16 bf16;
typedef __attribute__((ext_vector_type(8))) __bf16 bf16x8;
typedef __attribute__((ext_vector_type(4))) __bf16 bf16x4;
typedef __attribute__((ext_vector_type(4))) float f32x4;

#define MFMA16(A, B, C) __builtin_amdgcn_mfma_f32_16x16x32_bf16(A, B, C, 0, 0, 0)

// async global->LDS, 16B per lane: dest = (wave-uniform base) + lane*16
#define GLOAD16(gp, lp)                                          \
  __builtin_amdgcn_global_load_lds(                              \
      (const __attribute__((address_space(1))) void*)(gp),       \
      (__attribute__((address_space(3))) void*)(lp), 16, 0, 0)

// ---------------------------------------------------------------------------
// Transpose + fp32->bf16 convert: out[N][K] = (bf16) in[K][N]
// ---------------------------------------------------------------------------
__global__ __launch_bounds__(256) void transpose_cvt_kernel(
    const float* __restrict__ in, bf16* __restrict__ out, int K, int N)
{
  __shared__ float tile[32][33];
  const int kt = blockIdx.y * 32;
  const int nt = blockIdx.x * 32;
  const int tx = threadIdx.x, ty = threadIdx.y;
#pragma unroll
  for (int j = 0; j < 4; ++j)
    tile[ty + j * 8][tx] = in[(size_t)(kt + ty + j * 8) * N + nt + tx];
  __syncthreads();
#pragma unroll
  for (int j = 0; j < 4; ++j)
    out[(size_t)(nt + ty + j * 8) * K + kt + tx] = (bf16)tile[tx][ty + j * 8];
}

// ---------------------------------------------------------------------------
// LayerNorm (eps=1e-3), fp32 in -> bf16 out. One block per row of 1024.
// ---------------------------------------------------------------------------
__global__ __launch_bounds__(256) void ln_kernel(
    const float* __restrict__ in, const float* __restrict__ gamma,
    const float* __restrict__ beta, bf16* __restrict__ out)
{
  const int row = blockIdx.x;
  const int t = threadIdx.x;
  const float4 v = ((const float4*)(in + (size_t)row * 1024))[t];
  float s = v.x + v.y + v.z + v.w;
  float sq = v.x * v.x + v.y * v.y + v.z * v.z + v.w * v.w;
#pragma unroll
  for (int m = 1; m < 64; m <<= 1) {
    s += __shfl_xor(s, m);
    sq += __shfl_xor(sq, m);
  }
  __shared__ float ssum[4], ssq[4];
  const int w = t >> 6;
  if ((t & 63) == 0) { ssum[w] = s; ssq[w] = sq; }
  __syncthreads();
  s = ssum[0] + ssum[1] + ssum[2] + ssum[3];
  sq = ssq[0] + ssq[1] + ssq[2] + ssq[3];
  const float mu = s * (1.0f / 1024.0f);
  const float var = sq * (1.0f / 1024.0f) - mu * mu;
  const float rs = rsqrtf(var + 1e-3f);
  const float4 g = ((const float4*)gamma)[t];
  const float4 b = ((const float4*)beta)[t];
  bf16x4 o;
  o[0] = (bf16)((v.x - mu) * rs * g.x + b.x);
  o[1] = (bf16)((v.y - mu) * rs * g.y + b.y);
  o[2] = (bf16)((v.z - mu) * rs * g.z + b.z);
  o[3] = (bf16)((v.w - mu) * rs * g.w + b.w);
  *(bf16x4*)(out + (size_t)row * 1024 + t * 4) = o;
}

// ---------------------------------------------------------------------------
// GEMM: C[M,N] = epilogue(A[M,K] @ Bt[N,K]^T + bias)
// m97 structure: global_load_lds(16B) staging into linear LDS [rows][32],
// double-buffered, one __syncthreads per K-step (stage issued before MFMA).
// BN=128: 2x2 waves of 64x64.  BN=64: 2x2 waves of 64x32.
// EPI 1: bf16 relu -> out0
// EPI 2: f32 out = acc + bias0 + resid -> outf
// EPI 4: fused QKV: col<1024 -> out0(+bias0); <2048 -> out1(+bias1);
//        else V stored per-head transposed [b][h][d][t] -> out2(+bias2)
// ---------------------------------------------------------------------------
template <int BN, int EPI>
__global__ __launch_bounds__(256) void gemm_bt(
    const bf16* __restrict__ A, const bf16* __restrict__ Bt,
    const float* __restrict__ bias0, const float* __restrict__ bias1,
    const float* __restrict__ bias2, const float* __restrict__ resid,
    bf16* __restrict__ out0, bf16* __restrict__ out1, bf16* __restrict__ out2,
    float* __restrict__ outf, int M, int N, int K)
{
  constexpr int WN = BN / 2;   // wave tile cols
  constexpr int NJ = WN / 16;  // col fragments per wave
  __shared__ bf16 As[2][128 * 32];
  __shared__ bf16 Bs[2][BN * 32];
  const int tid = threadIdx.x;
  const int lane = tid & 63, w = tid >> 6;
  const int wr = w >> 1, wc = w & 1;
  const int g = lane >> 4, lr = lane & 15;
  const int brow = blockIdx.y * 128, bcol = blockIdx.x * BN;

  f32x4 acc[4][NJ] = {};

  const int lrow = lane >> 2;          // staging: lane -> row-in-16-group
  const int lcol = (lane & 3) * 8;     // staging: lane -> col (elements)

  auto stage = [&](int buf, int k0) {
#pragma unroll
    for (int j = 0; j < 2; ++j) {
      const int row0 = w * 32 + j * 16;
      GLOAD16(A + (size_t)(brow + row0 + lrow) * K + k0 + lcol,
              &As[buf][row0 * 32]);
    }
    if constexpr (BN == 128) {
#pragma unroll
      for (int j = 0; j < 2; ++j) {
        const int row0 = w * 32 + j * 16;
        GLOAD16(Bt + (size_t)(bcol + row0 + lrow) * K + k0 + lcol,
                &Bs[buf][row0 * 32]);
      }
    } else {
      const int row0 = w * 16;
      GLOAD16(Bt + (size_t)(bcol + row0 + lrow) * K + k0 + lcol,
              &Bs[buf][row0 * 32]);
    }
  };

  const int nk = K >> 5;
  stage(0, 0);
  __syncthreads();
  int cur = 0;
  for (int t = 0; t < nk; ++t) {
    if (t + 1 < nk) stage(cur ^ 1, (t + 1) << 5);  // async next-tile prefetch
    bf16x8 afr[4], bfr[NJ];
#pragma unroll
    for (int i = 0; i < 4; ++i)
      afr[i] = *(const bf16x8*)&As[cur][(wr * 64 + i * 16 + lr) * 32 + g * 8];
#pragma unroll
    for (int j = 0; j < NJ; ++j)
      bfr[j] = *(const bf16x8*)&Bs[cur][(wc * WN + j * 16 + lr) * 32 + g * 8];
#pragma unroll
    for (int i = 0; i < 4; ++i)
#pragma unroll
      for (int j = 0; j < NJ; ++j)
        acc[i][j] = MFMA16(afr[i], bfr[j], acc[i][j]);
    if (t + 1 < nk) {
      __syncthreads();  // drains prefetch; also protects buf reuse
      cur ^= 1;
    }
  }

#pragma unroll
  for (int i = 0; i < 4; ++i) {
#pragma unroll
    for (int j = 0; j < NJ; ++j) {
      const int r0 = brow + wr * 64 + i * 16 + g * 4;
      const int c = bcol + wc * WN + j * 16 + lr;
      if constexpr (EPI == 1) {
        const float bv = bias0[c];
#pragma unroll
        for (int rr = 0; rr < 4; ++rr)
          out0[(size_t)(r0 + rr) * N + c] = (bf16)fmaxf(acc[i][j][rr] + bv, 0.0f);
      } else if constexpr (EPI == 2) {
        const float bv = bias0[c];
#pragma unroll
        for (int rr = 0; rr < 4; ++rr) {
          const size_t idx = (size_t)(r0 + rr) * N + c;
          outf[idx] = acc[i][j][rr] + bv + resid[idx];
        }
      } else {  // EPI 4: fused QKV
        const int sub = c >> 10;  // block-uniform (128-col tiles)
        const int c1 = c & 1023;
        if (sub == 0) {
          const float bv = bias0[c1];
#pragma unroll
          for (int rr = 0; rr < 4; ++rr)
            out0[(size_t)(r0 + rr) * 1024 + c1] = (bf16)(acc[i][j][rr] + bv);
        } else if (sub == 1) {
          const float bv = bias1[c1];
#pragma unroll
          for (int rr = 0; rr < 4; ++rr)
            out1[(size_t)(r0 + rr) * 1024 + c1] = (bf16)(acc[i][j][rr] + bv);
        } else {
          const float bv = bias2[c1];
          const int bb = r0 >> 11, t0 = r0 & 2047;
          const int hh = c1 >> 6, dd = c1 & 63;
          bf16x4 pk;
#pragma unroll
          for (int rr = 0; rr < 4; ++rr) pk[rr] = (bf16)(acc[i][j][rr] + bv);
          *(bf16x4*)(out2 + ((size_t)((bb * 16 + hh) * 64 + dd)) * 2048 + t0) = pk;
        }
      }
    }
  }
}

// ---------------------------------------------------------------------------
// Causal flash attention, S^T formulation: per lane one q-row (q = lane&15).
// Grid (32,32): qt = (bx+by)&31 for CU load balance. Block: 4 waves x 16 q.
// q,k: [4096][1024] bf16 ; vt: [b][h][64 d][2048 t] bf16 ; ctx: [4096][1024]
// K/V LDS tiles [64 rows][64 bf16] with XOR-swizzled 16B slots (T2/G4).
// ---------------------------------------------------------------------------
__global__ __launch_bounds__(256) void attn_kernel(
    const bf16* __restrict__ q, const bf16* __restrict__ kmat,
    const bf16* __restrict__ vt, bf16* __restrict__ ctx)
{
  __shared__ bf16 Ks[64 * 64];
  __shared__ bf16 Vs[64 * 64];
  __shared__ bf16 Pq[4][16][88];  // per-wave P [q][s], stride 88
  const int qt = (blockIdx.x + blockIdx.y) & 31;
  const int bh = blockIdx.y;
  const int b_ = bh >> 4, h_ = bh & 15;
  const int qb = qt * 64;
  const int tid = threadIdx.x;
  const int lane = tid & 63, w = tid >> 6;
  const int g = lane >> 4, lr = lane & 15;
  const int qrow = qb + w * 16 + lr;  // this lane's q row (S^T layout)

  bf16x8 qf[2];
  {
    const bf16* qp = q + (size_t)(b_ * 2048 + qrow) * 1024 + h_ * 64 + g * 8;
    qf[0] = *(const bf16x8*)qp;
    qf[1] = *(const bf16x8*)(qp + 32);
  }

  f32x4 o[4] = {};
  float m = -1e30f, l = 0.f;

  const int srow = tid >> 2;            // staging row 0..63
  const int c16 = (tid & 3) * 16;       // staging col (elements)
  const int rb = srow * 128;            // row byte base in LDS tile
  const int sw = (srow & 7) << 4;       // XOR swizzle
  const bf16* kbase = kmat + (size_t)(b_ * 2048) * 1024 + h_ * 64;
  const bf16* vbase = vt + (size_t)(b_ * 16 + h_) * 64 * 2048;
  const bf16* kp0 = kbase + (size_t)srow * 1024 + c16;
  const bf16* vp0 = vbase + (size_t)srow * 2048 + c16;

  bf16x8 k0 = *(const bf16x8*)kp0;
  bf16x8 k1 = *(const bf16x8*)(kp0 + 8);
  bf16x8 v0 = *(const bf16x8*)vp0;
  bf16x8 v1 = *(const bf16x8*)(vp0 + 8);

  for (int s0 = 0; s0 <= qb; s0 += 64) {
    *(bf16x8*)((char*)Ks + ((rb + c16 * 2) ^ sw)) = k0;
    *(bf16x8*)((char*)Ks + ((rb + c16 * 2 + 16) ^ sw)) = k1;
    *(bf16x8*)((char*)Vs + ((rb + c16 * 2) ^ sw)) = v0;
    *(bf16x8*)((char*)Vs + ((rb + c16 * 2 + 16) ^ sw)) = v1;
    __syncthreads();
    if (s0 < qb) {  // prefetch next K/V tile into regs during compute
      const bf16* kp = kp0 + (size_t)(s0 + 64) * 1024;
      k0 = *(const bf16x8*)kp;
      k1 = *(const bf16x8*)(kp + 8);
      const bf16* vp = vp0 + (s0 + 64);
      v0 = *(const bf16x8*)vp;
      v1 = *(const bf16x8*)(vp + 8);
    }

    // S^T = K @ Q^T : lane holds S[q=qrow][s = s0 + 16n + 4g + r]
    f32x4 st[4];
#pragma unroll
    for (int n = 0; n < 4; ++n) {
      f32x4 z = {};
#pragma unroll
      for (int kk = 0; kk < 2; ++kk) {
        const int row = n * 16 + lr;
        bf16x8 ak = *(const bf16x8*)((char*)Ks +
            ((row * 128 + kk * 64 + g * 16) ^ ((lr & 7) << 4)));
        z = MFMA16(ak, qf[kk], z);
      }
      st[n] = z;
    }

    const bool needmask = (s0 == qb);
    float pm = -1e30f;
#pragma unroll
    for (int n = 0; n < 4; ++n)
#pragma unroll
      for (int r = 0; r < 4; ++r) {
        float sv = st[n][r] * 0.125f;  // 1/sqrt(64)
        if (needmask && (s0 + n * 16 + g * 4 + r > qrow)) sv = -1e30f;
        st[n][r] = sv;
        pm = fmaxf(pm, sv);
      }
    pm = fmaxf(pm, __shfl_xor(pm, 16));
    pm = fmaxf(pm, __shfl_xor(pm, 32));
    const float mn = fmaxf(m, pm);
    const float alpha = __expf(m - mn);
    m = mn;

    float rs = 0.f;
#pragma unroll
    for (int n = 0; n < 4; ++n) {
      bf16x4 pk;
#pragma unroll
      for (int r = 0; r < 4; ++r) {
        const float p = __expf(st[n][r] - mn);
        rs += p;
        pk[r] = (bf16)p;
      }
      *(bf16x4*)&Pq[w][lr][n * 16 + g * 4] = pk;  // P[q][s], s consecutive
    }
    rs += __shfl_xor(rs, 16);
    rs += __shfl_xor(rs, 32);
    l = l * alpha + rs;

    float av[4];
#pragma unroll
    for (int r = 0; r < 4; ++r) av[r] = __shfl(alpha, g * 4 + r);
#pragma unroll
    for (int n = 0; n < 4; ++n)
#pragma unroll
      for (int r = 0; r < 4; ++r) o[n][r] *= av[r];

    bf16x8 pa[2];
#pragma unroll
    for (int kk = 0; kk < 2; ++kk)
      pa[kk] = *(const bf16x8*)&Pq[w][lr][kk * 32 + g * 8];
#pragma unroll
    for (int n = 0; n < 4; ++n) {
      const int row = n * 16 + lr;
#pragma unroll
      for (int kk = 0; kk < 2; ++kk) {
        bf16x8 bv = *(const bf16x8*)((char*)Vs +
            ((row * 128 + kk * 64 + g * 16) ^ ((lr & 7) << 4)));
        o[n] = MFMA16(pa[kk], bv, o[n]);
      }
    }
    __syncthreads();
  }

  float lq[4];
#pragma unroll
  for (int r = 0; r < 4; ++r) lq[r] = __shfl(l, g * 4 + r);
#pragma unroll
  for (int r = 0; r < 4; ++r) {
    const float inv = 1.0f / lq[r];
#pragma unroll
    for (int n = 0; n < 4; ++n)
      ctx[(size_t)(b_ * 2048 + qb + w * 16 + g * 4 + r) * 1024 + h_ * 64 + n * 16 + lr] =
          (bf16)(o[n][r] * inv);
  }
}

// ---------------------------------------------------------------------------
extern "C" void kernel_launch(void* const* d_in, const int* in_sizes, int n_in,
                              void* d_out, int out_size, void* d_ws, size_t ws_size,
                              hipStream_t stream)
{
  (void)in_sizes; (void)n_in; (void)out_size; (void)ws_size;
  const float* x   = (const float*)d_in[0];
  const float* Wq  = (const float*)d_in[1];
  const float* bq  = (const float*)d_in[2];
  const float* Wk  = (const float*)d_in[3];
  const float* bk  = (const float*)d_in[4];
  const float* Wv  = (const float*)d_in[5];
  const float* bv  = (const float*)d_in[6];
  const float* Wo  = (const float*)d_in[7];
  const float* bo  = (const float*)d_in[8];
  const float* W1  = (const float*)d_in[9];
  const float* b1  = (const float*)d_in[10];
  const float* W2  = (const float*)d_in[11];
  const float* b2  = (const float*)d_in[12];
  const float* g1  = (const float*)d_in[13];
  const float* be1 = (const float*)d_in[14];
  const float* g2  = (const float*)d_in[15];
  const float* be2 = (const float*)d_in[16];
  float* out = (float*)d_out;

  char* ws = (char*)d_ws;
  const size_t MB = 1024 * 1024;
  bf16* wqkv_t = (bf16*)(ws + 0 * MB);  // [3072][1024]: wq|wk|wv contiguous
  bf16* wq_t = (bf16*)(ws + 0 * MB);
  bf16* wk_t = (bf16*)(ws + 2 * MB);
  bf16* wv_t = (bf16*)(ws + 4 * MB);
  bf16* wo_t = (bf16*)(ws + 6 * MB);
  bf16* w1_t = (bf16*)(ws + 8 * MB);   // [4096][1024]
  bf16* w2_t = (bf16*)(ws + 16 * MB);  // [1024][4096]
  bf16* h1   = (bf16*)(ws + 24 * MB);  // [4096][1024]
  bf16* qbuf = (bf16*)(ws + 32 * MB);  // [4096][1024]
  bf16* kbuf = (bf16*)(ws + 40 * MB);  // [4096][1024]
  bf16* vtb  = (bf16*)(ws + 48 * MB);  // [2][16][64][2048]
  bf16* ctx  = (bf16*)(ws + 56 * MB);  // [4096][1024]
  bf16* h2   = (bf16*)(ws + 64 * MB);  // [4096][1024]
  bf16* ff1  = (bf16*)(ws + 24 * MB);  // [4096][4096], overlays h1/q/k/vtb (dead)

  const dim3 tb(32, 8);
  transpose_cvt_kernel<<<dim3(32, 32), tb, 0, stream>>>(Wq, wq_t, 1024, 1024);
  transpose_cvt_kernel<<<dim3(32, 32), tb, 0, stream>>>(Wk, wk_t, 1024, 1024);
  transpose_cvt_kernel<<<dim3(32, 32), tb, 0, stream>>>(Wv, wv_t, 1024, 1024);
  transpose_cvt_kernel<<<dim3(32, 32), tb, 0, stream>>>(Wo, wo_t, 1024, 1024);
  transpose_cvt_kernel<<<dim3(128, 32), tb, 0, stream>>>(W1, w1_t, 1024, 4096);
  transpose_cvt_kernel<<<dim3(32, 128), tb, 0, stream>>>(W2, w2_t, 4096, 1024);

  ln_kernel<<<4096, 256, 0, stream>>>(x, g1, be1, h1);

  // fused QKV: [4096,1024] @ [1024,3072] -> q,k,v(transposed)
  gemm_bt<128, 4><<<dim3(24, 32), 256, 0, stream>>>(
      h1, wqkv_t, bq, bk, bv, nullptr, qbuf, kbuf, vtb, nullptr, 4096, 3072, 1024);

  attn_kernel<<<dim3(32, 32), 256, 0, stream>>>(qbuf, kbuf, vtb, ctx);

  // x2 = x + ctx@Wo + bo -> d_out (fp32)
  gemm_bt<64, 2><<<dim3(16, 32), 256, 0, stream>>>(
      ctx, wo_t, bo, nullptr, nullptr, x, nullptr, nullptr, nullptr, out, 4096, 1024, 1024);

  ln_kernel<<<4096, 256, 0, stream>>>(out, g2, be2, h2);

  gemm_bt<128, 1><<<dim3(32, 32), 256, 0, stream>>>(
      h2, w1_t, b1, nullptr, nullptr, nullptr, ff1, nullptr, nullptr, nullptr, 4096, 4096, 1024);

  // out = x2 + ff1@W2 + b2 (in-place read+write of d_out, 1 thread/element)
  gemm_bt<64, 2><<<dim3(16, 32), 256, 0, stream>>>(
      ff1, w2_t, b2, nullptr, nullptr, out, nullptr, nullptr, nullptr, out, 4096, 1024, 4096);
}

// Round 4
// 255.179 us; speedup vs baseline: 1.0964x; 1.0964x over previous
//
#include <hip/hip_runtime.h>

typedef __bf16 bf16;
typedef __attribute__((ext_vector_type(8))) __bf16 bf16x8;
typedef __attribute__((ext_vector_type(4))) __bf16 bf16x4;
typedef __attribute__((ext_vector_type(4))) float f32x4;

#define MFMA16(A, B, C) __builtin_amdgcn_mfma_f32_16x16x32_bf16(A, B, C, 0, 0, 0)

// async global->LDS, 16B per lane: dest = (wave-uniform base) + lane*16
#define GLOAD16(gp, lp)                                          \
  __builtin_amdgcn_global_load_lds(                              \
      (const __attribute__((address_space(1))) void*)(gp),       \
      (__attribute__((address_space(3))) void*)(lp), 16, 0, 0)

// ---------------------------------------------------------------------------
// Transpose + fp32->bf16 convert: out[N][K] = (bf16) in[K][N]
// ---------------------------------------------------------------------------
__global__ __launch_bounds__(256) void transpose_cvt_kernel(
    const float* __restrict__ in, bf16* __restrict__ out, int K, int N)
{
  __shared__ float tile[32][33];
  const int kt = blockIdx.y * 32;
  const int nt = blockIdx.x * 32;
  const int tx = threadIdx.x, ty = threadIdx.y;
#pragma unroll
  for (int j = 0; j < 4; ++j)
    tile[ty + j * 8][tx] = in[(size_t)(kt + ty + j * 8) * N + nt + tx];
  __syncthreads();
#pragma unroll
  for (int j = 0; j < 4; ++j)
    out[(size_t)(nt + ty + j * 8) * K + kt + tx] = (bf16)tile[tx][ty + j * 8];
}

// ---------------------------------------------------------------------------
// LayerNorm (eps=1e-3), fp32 in -> bf16 out. One block per row of 1024.
// ---------------------------------------------------------------------------
__global__ __launch_bounds__(256) void ln_kernel(
    const float* __restrict__ in, const float* __restrict__ gamma,
    const float* __restrict__ beta, bf16* __restrict__ out)
{
  const int row = blockIdx.x;
  const int t = threadIdx.x;
  const float4 v = ((const float4*)(in + (size_t)row * 1024))[t];
  float s = v.x + v.y + v.z + v.w;
  float sq = v.x * v.x + v.y * v.y + v.z * v.z + v.w * v.w;
#pragma unroll
  for (int m = 1; m < 64; m <<= 1) {
    s += __shfl_xor(s, m);
    sq += __shfl_xor(sq, m);
  }
  __shared__ float ssum[4], ssq[4];
  const int w = t >> 6;
  if ((t & 63) == 0) { ssum[w] = s; ssq[w] = sq; }
  __syncthreads();
  s = ssum[0] + ssum[1] + ssum[2] + ssum[3];
  sq = ssq[0] + ssq[1] + ssq[2] + ssq[3];
  const float mu = s * (1.0f / 1024.0f);
  const float var = sq * (1.0f / 1024.0f) - mu * mu;
  const float rs = rsqrtf(var + 1e-3f);
  const float4 g = ((const float4*)gamma)[t];
  const float4 b = ((const float4*)beta)[t];
  bf16x4 o;
  o[0] = (bf16)((v.x - mu) * rs * g.x + b.x);
  o[1] = (bf16)((v.y - mu) * rs * g.y + b.y);
  o[2] = (bf16)((v.z - mu) * rs * g.z + b.z);
  o[3] = (bf16)((v.w - mu) * rs * g.w + b.w);
  *(bf16x4*)(out + (size_t)row * 1024 + t * 4) = o;
}

// ---------------------------------------------------------------------------
// GEMM: C[M,N] = epilogue(A[M,K] @ Bt[N,K]^T + bias)
// T3+T4 pipeline: 3 LDS buffers, prefetch distance 2 via global_load_lds(16B),
// counted s_waitcnt vmcnt(S) (never 0 in main loop) + raw s_barrier.
// BN=128: 2x2 waves of 64x64 (S=4 loads/wave).  BN=64: 64x32 (S=3).
// EPI 1: bf16 relu -> out0
// EPI 2: f32 out = acc + bias0 + resid -> outf
// EPI 4: fused QKV: col<1024 -> out0(+bias0); <2048 -> out1(+bias1);
//        else V stored per-head transposed [b][h][d][t] -> out2(+bias2)
// ---------------------------------------------------------------------------
template <int BN, int EPI>
__global__ __launch_bounds__(256) void gemm_bt(
    const bf16* __restrict__ A, const bf16* __restrict__ Bt,
    const float* __restrict__ bias0, const float* __restrict__ bias1,
    const float* __restrict__ bias2, const float* __restrict__ resid,
    bf16* __restrict__ out0, bf16* __restrict__ out1, bf16* __restrict__ out2,
    float* __restrict__ outf, int M, int N, int K)
{
  constexpr int WN = BN / 2;   // wave tile cols
  constexpr int NJ = WN / 16;  // col fragments per wave
  __shared__ bf16 As[3][128 * 32];
  __shared__ bf16 Bs[3][BN * 32];
  const int tid = threadIdx.x;
  const int lane = tid & 63, w = tid >> 6;
  const int wr = w >> 1, wc = w & 1;
  const int g = lane >> 4, lr = lane & 15;
  const int brow = blockIdx.y * 128, bcol = blockIdx.x * BN;

  f32x4 acc[4][NJ] = {};

  const int lrow = lane >> 2;          // staging: lane -> row-in-16-group
  const int lcol = (lane & 3) * 8;     // staging: lane -> col (elements)

  auto stage = [&](int buf, int k0) {
#pragma unroll
    for (int j = 0; j < 2; ++j) {
      const int row0 = w * 32 + j * 16;
      GLOAD16(A + (size_t)(brow + row0 + lrow) * K + k0 + lcol,
              &As[buf][row0 * 32]);
    }
    if constexpr (BN == 128) {
#pragma unroll
      for (int j = 0; j < 2; ++j) {
        const int row0 = w * 32 + j * 16;
        GLOAD16(Bt + (size_t)(bcol + row0 + lrow) * K + k0 + lcol,
                &Bs[buf][row0 * 32]);
      }
    } else {
      const int row0 = w * 16;
      GLOAD16(Bt + (size_t)(bcol + row0 + lrow) * K + k0 + lcol,
              &Bs[buf][row0 * 32]);
    }
  };

  const int nk = K >> 5;
  stage(0, 0);
  stage(1, 32);
  int cur = 0;
  for (int t = 0; t < nk; ++t) {
    // Wait for tile t's stage (issued at t-2): allow the S newest (tile t+1's
    // stage) to stay in flight. Last iter: nothing newer in flight -> drain.
    if (t + 1 < nk) {
      if constexpr (BN == 128)
        asm volatile("s_waitcnt vmcnt(4)" ::: "memory");
      else
        asm volatile("s_waitcnt vmcnt(3)" ::: "memory");
    } else {
      asm volatile("s_waitcnt vmcnt(0)" ::: "memory");
    }
    __builtin_amdgcn_s_barrier();
    __builtin_amdgcn_sched_barrier(0);  // pin reads/stage below the barrier

    bf16x8 afr[4], bfr[NJ];
#pragma unroll
    for (int i = 0; i < 4; ++i)
      afr[i] = *(const bf16x8*)&As[cur][(wr * 64 + i * 16 + lr) * 32 + g * 8];
#pragma unroll
    for (int j = 0; j < NJ; ++j)
      bfr[j] = *(const bf16x8*)&Bs[cur][(wc * WN + j * 16 + lr) * 32 + g * 8];

    if (t + 2 < nk) {  // prefetch tile t+2 into the buffer freed at t-1
      int nb = cur + 2;
      if (nb >= 3) nb -= 3;
      stage(nb, (t + 2) << 5);
    }

#pragma unroll
    for (int i = 0; i < 4; ++i)
#pragma unroll
      for (int j = 0; j < NJ; ++j)
        acc[i][j] = MFMA16(afr[i], bfr[j], acc[i][j]);

    ++cur;
    if (cur == 3) cur = 0;
  }

#pragma unroll
  for (int i = 0; i < 4; ++i) {
#pragma unroll
    for (int j = 0; j < NJ; ++j) {
      const int r0 = brow + wr * 64 + i * 16 + g * 4;
      const int c = bcol + wc * WN + j * 16 + lr;
      if constexpr (EPI == 1) {
        const float bv = bias0[c];
#pragma unroll
        for (int rr = 0; rr < 4; ++rr)
          out0[(size_t)(r0 + rr) * N + c] = (bf16)fmaxf(acc[i][j][rr] + bv, 0.0f);
      } else if constexpr (EPI == 2) {
        const float bv = bias0[c];
#pragma unroll
        for (int rr = 0; rr < 4; ++rr) {
          const size_t idx = (size_t)(r0 + rr) * N + c;
          outf[idx] = acc[i][j][rr] + bv + resid[idx];
        }
      } else {  // EPI 4: fused QKV
        const int sub = c >> 10;  // block-uniform (128-col tiles)
        const int c1 = c & 1023;
        if (sub == 0) {
          const float bv = bias0[c1];
#pragma unroll
          for (int rr = 0; rr < 4; ++rr)
            out0[(size_t)(r0 + rr) * 1024 + c1] = (bf16)(acc[i][j][rr] + bv);
        } else if (sub == 1) {
          const float bv = bias1[c1];
#pragma unroll
          for (int rr = 0; rr < 4; ++rr)
            out1[(size_t)(r0 + rr) * 1024 + c1] = (bf16)(acc[i][j][rr] + bv);
        } else {
          const float bv = bias2[c1];
          const int bb = r0 >> 11, t0 = r0 & 2047;
          const int hh = c1 >> 6, dd = c1 & 63;
          bf16x4 pk;
#pragma unroll
          for (int rr = 0; rr < 4; ++rr) pk[rr] = (bf16)(acc[i][j][rr] + bv);
          *(bf16x4*)(out2 + ((size_t)((bb * 16 + hh) * 64 + dd)) * 2048 + t0) = pk;
        }
      }
    }
  }
}

// ---------------------------------------------------------------------------
// Causal flash attention, S^T formulation: per lane one q-row (q = lane&15).
// Grid (32,32): qt = (bx+by)&31 for CU load balance. Block: 4 waves x 16 q.
// q,k: [4096][1024] bf16 ; vt: [b][h][64 d][2048 t] bf16 ; ctx: [4096][1024]
// K/V LDS tiles [64 rows][64 bf16] with XOR-swizzled 16B slots (T2/G4).
// ---------------------------------------------------------------------------
__global__ __launch_bounds__(256) void attn_kernel(
    const bf16* __restrict__ q, const bf16* __restrict__ kmat,
    const bf16* __restrict__ vt, bf16* __restrict__ ctx)
{
  __shared__ bf16 Ks[64 * 64];
  __shared__ bf16 Vs[64 * 64];
  __shared__ bf16 Pq[4][16][88];  // per-wave P [q][s], stride 88
  const int qt = (blockIdx.x + blockIdx.y) & 31;
  const int bh = blockIdx.y;
  const int b_ = bh >> 4, h_ = bh & 15;
  const int qb = qt * 64;
  const int tid = threadIdx.x;
  const int lane = tid & 63, w = tid >> 6;
  const int g = lane >> 4, lr = lane & 15;
  const int qrow = qb + w * 16 + lr;  // this lane's q row (S^T layout)

  bf16x8 qf[2];
  {
    const bf16* qp = q + (size_t)(b_ * 2048 + qrow) * 1024 + h_ * 64 + g * 8;
    qf[0] = *(const bf16x8*)qp;
    qf[1] = *(const bf16x8*)(qp + 32);
  }

  f32x4 o[4] = {};
  float m = -1e30f, l = 0.f;

  const int srow = tid >> 2;            // staging row 0..63
  const int c16 = (tid & 3) * 16;       // staging col (elements)
  const int rb = srow * 128;            // row byte base in LDS tile
  const int sw = (srow & 7) << 4;       // XOR swizzle
  const bf16* kbase = kmat + (size_t)(b_ * 2048) * 1024 + h_ * 64;
  const bf16* vbase = vt + (size_t)(b_ * 16 + h_) * 64 * 2048;
  const bf16* kp0 = kbase + (size_t)srow * 1024 + c16;
  const bf16* vp0 = vbase + (size_t)srow * 2048 + c16;

  bf16x8 k0 = *(const bf16x8*)kp0;
  bf16x8 k1 = *(const bf16x8*)(kp0 + 8);
  bf16x8 v0 = *(const bf16x8*)vp0;
  bf16x8 v1 = *(const bf16x8*)(vp0 + 8);

  for (int s0 = 0; s0 <= qb; s0 += 64) {
    *(bf16x8*)((char*)Ks + ((rb + c16 * 2) ^ sw)) = k0;
    *(bf16x8*)((char*)Ks + ((rb + c16 * 2 + 16) ^ sw)) = k1;
    *(bf16x8*)((char*)Vs + ((rb + c16 * 2) ^ sw)) = v0;
    *(bf16x8*)((char*)Vs + ((rb + c16 * 2 + 16) ^ sw)) = v1;
    __syncthreads();
    if (s0 < qb) {  // prefetch next K/V tile into regs during compute
      const bf16* kp = kp0 + (size_t)(s0 + 64) * 1024;
      k0 = *(const bf16x8*)kp;
      k1 = *(const bf16x8*)(kp + 8);
      const bf16* vp = vp0 + (s0 + 64);
      v0 = *(const bf16x8*)vp;
      v1 = *(const bf16x8*)(vp + 8);
    }

    // S^T = K @ Q^T : lane holds S[q=qrow][s = s0 + 16n + 4g + r]
    f32x4 st[4];
#pragma unroll
    for (int n = 0; n < 4; ++n) {
      f32x4 z = {};
#pragma unroll
      for (int kk = 0; kk < 2; ++kk) {
        const int row = n * 16 + lr;
        bf16x8 ak = *(const bf16x8*)((char*)Ks +
            ((row * 128 + kk * 64 + g * 16) ^ ((lr & 7) << 4)));
        z = MFMA16(ak, qf[kk], z);
      }
      st[n] = z;
    }

    const bool needmask = (s0 == qb);
    float pm = -1e30f;
#pragma unroll
    for (int n = 0; n < 4; ++n)
#pragma unroll
      for (int r = 0; r < 4; ++r) {
        float sv = st[n][r] * 0.125f;  // 1/sqrt(64)
        if (needmask && (s0 + n * 16 + g * 4 + r > qrow)) sv = -1e30f;
        st[n][r] = sv;
        pm = fmaxf(pm, sv);
      }
    pm = fmaxf(pm, __shfl_xor(pm, 16));
    pm = fmaxf(pm, __shfl_xor(pm, 32));
    const float mn = fmaxf(m, pm);
    const float alpha = __expf(m - mn);
    m = mn;

    float rs = 0.f;
#pragma unroll
    for (int n = 0; n < 4; ++n) {
      bf16x4 pk;
#pragma unroll
      for (int r = 0; r < 4; ++r) {
        const float p = __expf(st[n][r] - mn);
        rs += p;
        pk[r] = (bf16)p;
      }
      *(bf16x4*)&Pq[w][lr][n * 16 + g * 4] = pk;  // P[q][s], s consecutive
    }
    rs += __shfl_xor(rs, 16);
    rs += __shfl_xor(rs, 32);
    l = l * alpha + rs;

    float av[4];
#pragma unroll
    for (int r = 0; r < 4; ++r) av[r] = __shfl(alpha, g * 4 + r);
#pragma unroll
    for (int n = 0; n < 4; ++n)
#pragma unroll
      for (int r = 0; r < 4; ++r) o[n][r] *= av[r];

    bf16x8 pa[2];
#pragma unroll
    for (int kk = 0; kk < 2; ++kk)
      pa[kk] = *(const bf16x8*)&Pq[w][lr][kk * 32 + g * 8];
#pragma unroll
    for (int n = 0; n < 4; ++n) {
      const int row = n * 16 + lr;
#pragma unroll
      for (int kk = 0; kk < 2; ++kk) {
        bf16x8 bv = *(const bf16x8*)((char*)Vs +
            ((row * 128 + kk * 64 + g * 16) ^ ((lr & 7) << 4)));
        o[n] = MFMA16(pa[kk], bv, o[n]);
      }
    }
    __syncthreads();
  }

  float lq[4];
#pragma unroll
  for (int r = 0; r < 4; ++r) lq[r] = __shfl(l, g * 4 + r);
#pragma unroll
  for (int r = 0; r < 4; ++r) {
    const float inv = 1.0f / lq[r];
#pragma unroll
    for (int n = 0; n < 4; ++n)
      ctx[(size_t)(b_ * 2048 + qb + w * 16 + g * 4 + r) * 1024 + h_ * 64 + n * 16 + lr] =
          (bf16)(o[n][r] * inv);
  }
}

// ---------------------------------------------------------------------------
extern "C" void kernel_launch(void* const* d_in, const int* in_sizes, int n_in,
                              void* d_out, int out_size, void* d_ws, size_t ws_size,
                              hipStream_t stream)
{
  (void)in_sizes; (void)n_in; (void)out_size; (void)ws_size;
  const float* x   = (const float*)d_in[0];
  const float* Wq  = (const float*)d_in[1];
  const float* bq  = (const float*)d_in[2];
  const float* Wk  = (const float*)d_in[3];
  const float* bk  = (const float*)d_in[4];
  const float* Wv  = (const float*)d_in[5];
  const float* bv  = (const float*)d_in[6];
  const float* Wo  = (const float*)d_in[7];
  const float* bo  = (const float*)d_in[8];
  const float* W1  = (const float*)d_in[9];
  const float* b1  = (const float*)d_in[10];
  const float* W2  = (const float*)d_in[11];
  const float* b2  = (const float*)d_in[12];
  const float* g1  = (const float*)d_in[13];
  const float* be1 = (const float*)d_in[14];
  const float* g2  = (const float*)d_in[15];
  const float* be2 = (const float*)d_in[16];
  float* out = (float*)d_out;

  char* ws = (char*)d_ws;
  const size_t MB = 1024 * 1024;
  bf16* wqkv_t = (bf16*)(ws + 0 * MB);  // [3072][1024]: wq|wk|wv contiguous
  bf16* wq_t = (bf16*)(ws + 0 * MB);
  bf16* wk_t = (bf16*)(ws + 2 * MB);
  bf16* wv_t = (bf16*)(ws + 4 * MB);
  bf16* wo_t = (bf16*)(ws + 6 * MB);
  bf16* w1_t = (bf16*)(ws + 8 * MB);   // [4096][1024]
  bf16* w2_t = (bf16*)(ws + 16 * MB);  // [1024][4096]
  bf16* h1   = (bf16*)(ws + 24 * MB);  // [4096][1024]
  bf16* qbuf = (bf16*)(ws + 32 * MB);  // [4096][1024]
  bf16* kbuf = (bf16*)(ws + 40 * MB);  // [4096][1024]
  bf16* vtb  = (bf16*)(ws + 48 * MB);  // [2][16][64][2048]
  bf16* ctx  = (bf16*)(ws + 56 * MB);  // [4096][1024]
  bf16* h2   = (bf16*)(ws + 64 * MB);  // [4096][1024]
  bf16* ff1  = (bf16*)(ws + 24 * MB);  // [4096][4096], overlays h1/q/k/vtb (dead)

  const dim3 tb(32, 8);
  transpose_cvt_kernel<<<dim3(32, 32), tb, 0, stream>>>(Wq, wq_t, 1024, 1024);
  transpose_cvt_kernel<<<dim3(32, 32), tb, 0, stream>>>(Wk, wk_t, 1024, 1024);
  transpose_cvt_kernel<<<dim3(32, 32), tb, 0, stream>>>(Wv, wv_t, 1024, 1024);
  transpose_cvt_kernel<<<dim3(32, 32), tb, 0, stream>>>(Wo, wo_t, 1024, 1024);
  transpose_cvt_kernel<<<dim3(128, 32), tb, 0, stream>>>(W1, w1_t, 1024, 4096);
  transpose_cvt_kernel<<<dim3(32, 128), tb, 0, stream>>>(W2, w2_t, 4096, 1024);

  ln_kernel<<<4096, 256, 0, stream>>>(x, g1, be1, h1);

  // fused QKV: [4096,1024] @ [1024,3072] -> q,k,v(transposed)
  gemm_bt<128, 4><<<dim3(24, 32), 256, 0, stream>>>(
      h1, wqkv_t, bq, bk, bv, nullptr, qbuf, kbuf, vtb, nullptr, 4096, 3072, 1024);

  attn_kernel<<<dim3(32, 32), 256, 0, stream>>>(qbuf, kbuf, vtb, ctx);

  // x2 = x + ctx@Wo + bo -> d_out (fp32)
  gemm_bt<64, 2><<<dim3(16, 32), 256, 0, stream>>>(
      ctx, wo_t, bo, nullptr, nullptr, x, nullptr, nullptr, nullptr, out, 4096, 1024, 1024);

  ln_kernel<<<4096, 256, 0, stream>>>(out, g2, be2, h2);

  gemm_bt<128, 1><<<dim3(32, 32), 256, 0, stream>>>(
      h2, w1_t, b1, nullptr, nullptr, nullptr, ff1, nullptr, nullptr, nullptr, 4096, 4096, 1024);

  // out = x2 + ff1@W2 + b2 (in-place read+write of d_out, 1 thread/element)
  gemm_bt<64, 2><<<dim3(16, 32), 256, 0, stream>>>(
      ff1, w2_t, b2, nullptr, nullptr, out, nullptr, nullptr, nullptr, out, 4096, 1024, 4096);
}

// Round 5
// 236.423 us; speedup vs baseline: 1.1834x; 1.0793x over previous
//
#include <hip/hip_runtime.h>

typedef __bf16 bf16;
typedef __attribute__((ext_vector_type(8))) __bf16 bf16x8;
typedef __attribute__((ext_vector_type(4))) __bf16 bf16x4;
typedef __attribute__((ext_vector_type(4))) float f32x4;

#define MFMA16(A, B, C) __builtin_amdgcn_mfma_f32_16x16x32_bf16(A, B, C, 0, 0, 0)

// async global->LDS, 16B per lane: dest = (wave-uniform base) + lane*16
#define GLOAD16(gp, lp)                                          \
  __builtin_amdgcn_global_load_lds(                              \
      (const __attribute__((address_space(1))) void*)(gp),       \
      (__attribute__((address_space(3))) void*)(lp), 16, 0, 0)

// ---------------------------------------------------------------------------
// Transpose + fp32->bf16 convert: out[N][K] = (bf16) in[K][N]
// ---------------------------------------------------------------------------
__global__ __launch_bounds__(256) void transpose_cvt_kernel(
    const float* __restrict__ in, bf16* __restrict__ out, int K, int N)
{
  __shared__ float tile[32][33];
  const int kt = blockIdx.y * 32;
  const int nt = blockIdx.x * 32;
  const int tx = threadIdx.x, ty = threadIdx.y;
#pragma unroll
  for (int j = 0; j < 4; ++j)
    tile[ty + j * 8][tx] = in[(size_t)(kt + ty + j * 8) * N + nt + tx];
  __syncthreads();
#pragma unroll
  for (int j = 0; j < 4; ++j)
    out[(size_t)(nt + ty + j * 8) * K + kt + tx] = (bf16)tile[tx][ty + j * 8];
}

// ---------------------------------------------------------------------------
// LayerNorm (eps=1e-3), fp32 in -> bf16 out. One block per row of 1024.
// ---------------------------------------------------------------------------
__global__ __launch_bounds__(256) void ln_kernel(
    const float* __restrict__ in, const float* __restrict__ gamma,
    const float* __restrict__ beta, bf16* __restrict__ out)
{
  const int row = blockIdx.x;
  const int t = threadIdx.x;
  const float4 v = ((const float4*)(in + (size_t)row * 1024))[t];
  float s = v.x + v.y + v.z + v.w;
  float sq = v.x * v.x + v.y * v.y + v.z * v.z + v.w * v.w;
#pragma unroll
  for (int m = 1; m < 64; m <<= 1) {
    s += __shfl_xor(s, m);
    sq += __shfl_xor(sq, m);
  }
  __shared__ float ssum[4], ssq[4];
  const int w = t >> 6;
  if ((t & 63) == 0) { ssum[w] = s; ssq[w] = sq; }
  __syncthreads();
  s = ssum[0] + ssum[1] + ssum[2] + ssum[3];
  sq = ssq[0] + ssq[1] + ssq[2] + ssq[3];
  const float mu = s * (1.0f / 1024.0f);
  const float var = sq * (1.0f / 1024.0f) - mu * mu;
  const float rs = rsqrtf(var + 1e-3f);
  const float4 g = ((const float4*)gamma)[t];
  const float4 b = ((const float4*)beta)[t];
  bf16x4 o;
  o[0] = (bf16)((v.x - mu) * rs * g.x + b.x);
  o[1] = (bf16)((v.y - mu) * rs * g.y + b.y);
  o[2] = (bf16)((v.z - mu) * rs * g.z + b.z);
  o[3] = (bf16)((v.w - mu) * rs * g.w + b.w);
  *(bf16x4*)(out + (size_t)row * 1024 + t * 4) = o;
}

// ---------------------------------------------------------------------------
// GEMM: C[M,N] = epilogue(A[M,K] @ Bt[N,K]^T + bias)
// T3+T4 pipeline: 3 LDS buffers, prefetch distance 2 via global_load_lds(16B),
// counted s_waitcnt vmcnt(S) (never 0 in main loop) + raw s_barrier.
// T2 swizzle (both-sides): linear LDS dest, source chunk = slot^(row&SMASK),
// ds_read col slot = chunk^(row&SMASK)  (XOR involution, rule #21).
// T5 setprio(1/0) around the MFMA cluster.
// BN=128: 2x2 waves of 64x64.  BN=64: 2x2 waves of 64x32.
// EPI 1: bf16 relu -> out0
// EPI 2: f32 out = acc + bias0 + resid -> outf
// EPI 4: fused QKV: col<1024 -> out0(+bias0); <2048 -> out1(+bias1);
//        else V stored per-head transposed [b][h][d][t] -> out2(+bias2)
// ---------------------------------------------------------------------------
template <int BN, int BK, int EPI>
__global__ __launch_bounds__(256) void gemm_bt(
    const bf16* __restrict__ A, const bf16* __restrict__ Bt,
    const float* __restrict__ bias0, const float* __restrict__ bias1,
    const float* __restrict__ bias2, const float* __restrict__ resid,
    bf16* __restrict__ out0, bf16* __restrict__ out1, bf16* __restrict__ out2,
    float* __restrict__ outf, int M, int N, int K)
{
  constexpr int WN = BN / 2;        // wave tile cols
  constexpr int NJ = WN / 16;       // col fragments per wave
  constexpr int KK = BK / 32;       // mfma k-substeps per K-step
  constexpr int NSLOT = BK / 8;     // 16B slots per LDS row
  constexpr int SMASK = NSLOT - 1;
  constexpr int RPL = 512 / BK;     // rows covered per gload16
  constexpr int ALOADS = 128 / (4 * RPL);
  constexpr int BLOADS = BN / (4 * RPL);
  constexpr int S = ALOADS + BLOADS;  // gloads per wave per stage

  __shared__ bf16 As[3][128 * BK];
  __shared__ bf16 Bs[3][BN * BK];
  const int tid = threadIdx.x;
  const int lane = tid & 63, w = tid >> 6;
  const int wr = w >> 1, wc = w & 1;
  const int g = lane >> 4, lr = lane & 15;
  const int brow = blockIdx.y * 128, bcol = blockIdx.x * BN;

  f32x4 acc[4][NJ] = {};

  const int lrow = lane / NSLOT;               // row within a gload group
  const int slot = lane & SMASK;               // this lane's linear LDS slot
  const int lcol = (slot ^ (lrow & SMASK)) * 8;  // swizzled source chunk

  auto stage = [&](int buf, int k0) {
#pragma unroll
    for (int j = 0; j < ALOADS; ++j) {
      const int row0 = w * 32 + j * RPL;
      GLOAD16(A + (size_t)(brow + row0 + lrow) * K + k0 + lcol,
              &As[buf][row0 * BK]);
    }
#pragma unroll
    for (int j = 0; j < BLOADS; ++j) {
      const int row0 = w * (BN / 4) + j * RPL;
      GLOAD16(Bt + (size_t)(bcol + row0 + lrow) * K + k0 + lcol,
              &Bs[buf][row0 * BK]);
    }
  };

  const int nk = K / BK;
  stage(0, 0);
  stage(1, BK);
  int cur = 0;
  for (int t = 0; t < nk; ++t) {
    // Wait for tile t's stage (issued at t-2); keep tile t+1's S loads in
    // flight (counted vmcnt, never 0 mid-loop). Last iter: drain.
    if (t + 1 < nk) {
      if constexpr (S == 3)
        asm volatile("s_waitcnt vmcnt(3)" ::: "memory");
      else if constexpr (S == 4)
        asm volatile("s_waitcnt vmcnt(4)" ::: "memory");
      else
        asm volatile("s_waitcnt vmcnt(6)" ::: "memory");
    } else {
      asm volatile("s_waitcnt vmcnt(0)" ::: "memory");
    }
    __builtin_amdgcn_s_barrier();
    __builtin_amdgcn_sched_barrier(0);  // pin reads/stage below the barrier

    bf16x8 afr[4][KK], bfr[NJ][KK];
#pragma unroll
    for (int i = 0; i < 4; ++i)
#pragma unroll
      for (int kk = 0; kk < KK; ++kk)
        afr[i][kk] = *(const bf16x8*)&As[cur][(wr * 64 + i * 16 + lr) * BK +
                                             (((kk * 4 + g) ^ (lr & SMASK)) * 8)];
#pragma unroll
    for (int j = 0; j < NJ; ++j)
#pragma unroll
      for (int kk = 0; kk < KK; ++kk)
        bfr[j][kk] = *(const bf16x8*)&Bs[cur][(wc * WN + j * 16 + lr) * BK +
                                             (((kk * 4 + g) ^ (lr & SMASK)) * 8)];

    if (t + 2 < nk) {  // prefetch tile t+2 into the buffer freed at t-1
      int nb = cur + 2;
      if (nb >= 3) nb -= 3;
      stage(nb, (t + 2) * BK);
    }

    __builtin_amdgcn_s_setprio(1);
#pragma unroll
    for (int kk = 0; kk < KK; ++kk)
#pragma unroll
      for (int i = 0; i < 4; ++i)
#pragma unroll
        for (int j = 0; j < NJ; ++j)
          acc[i][j] = MFMA16(afr[i][kk], bfr[j][kk], acc[i][j]);
    __builtin_amdgcn_s_setprio(0);

    ++cur;
    if (cur == 3) cur = 0;
  }

#pragma unroll
  for (int i = 0; i < 4; ++i) {
#pragma unroll
    for (int j = 0; j < NJ; ++j) {
      const int r0 = brow + wr * 64 + i * 16 + g * 4;
      const int c = bcol + wc * WN + j * 16 + lr;
      if constexpr (EPI == 1) {
        const float bv = bias0[c];
#pragma unroll
        for (int rr = 0; rr < 4; ++rr)
          out0[(size_t)(r0 + rr) * N + c] = (bf16)fmaxf(acc[i][j][rr] + bv, 0.0f);
      } else if constexpr (EPI == 2) {
        const float bv = bias0[c];
#pragma unroll
        for (int rr = 0; rr < 4; ++rr) {
          const size_t idx = (size_t)(r0 + rr) * N + c;
          outf[idx] = acc[i][j][rr] + bv + resid[idx];
        }
      } else {  // EPI 4: fused QKV
        const int sub = c >> 10;  // block-uniform (128-col tiles)
        const int c1 = c & 1023;
        if (sub == 0) {
          const float bv = bias0[c1];
#pragma unroll
          for (int rr = 0; rr < 4; ++rr)
            out0[(size_t)(r0 + rr) * 1024 + c1] = (bf16)(acc[i][j][rr] + bv);
        } else if (sub == 1) {
          const float bv = bias1[c1];
#pragma unroll
          for (int rr = 0; rr < 4; ++rr)
            out1[(size_t)(r0 + rr) * 1024 + c1] = (bf16)(acc[i][j][rr] + bv);
        } else {
          const float bv = bias2[c1];
          const int bb = r0 >> 11, t0 = r0 & 2047;
          const int hh = c1 >> 6, dd = c1 & 63;
          bf16x4 pk;
#pragma unroll
          for (int rr = 0; rr < 4; ++rr) pk[rr] = (bf16)(acc[i][j][rr] + bv);
          *(bf16x4*)(out2 + ((size_t)((bb * 16 + hh) * 64 + dd)) * 2048 + t0) = pk;
        }
      }
    }
  }
}

// ---------------------------------------------------------------------------
// Causal flash attention, S^T formulation: per lane one q-row (q = lane&15).
// Grid (32,32): qt = (bx+by)&31 for CU load balance. Block: 4 waves x 16 q.
// q,k: [4096][1024] bf16 ; vt: [b][h][64 d][2048 t] bf16 ; ctx: [4096][1024]
// K/V LDS tiles [64 rows][64 bf16] with XOR-swizzled 16B slots (T2/G4).
// ---------------------------------------------------------------------------
__global__ __launch_bounds__(256) void attn_kernel(
    const bf16* __restrict__ q, const bf16* __restrict__ kmat,
    const bf16* __restrict__ vt, bf16* __restrict__ ctx)
{
  __shared__ bf16 Ks[64 * 64];
  __shared__ bf16 Vs[64 * 64];
  __shared__ bf16 Pq[4][16][88];  // per-wave P [q][s], stride 88
  const int qt = (blockIdx.x + blockIdx.y) & 31;
  const int bh = blockIdx.y;
  const int b_ = bh >> 4, h_ = bh & 15;
  const int qb = qt * 64;
  const int tid = threadIdx.x;
  const int lane = tid & 63, w = tid >> 6;
  const int g = lane >> 4, lr = lane & 15;
  const int qrow = qb + w * 16 + lr;  // this lane's q row (S^T layout)

  bf16x8 qf[2];
  {
    const bf16* qp = q + (size_t)(b_ * 2048 + qrow) * 1024 + h_ * 64 + g * 8;
    qf[0] = *(const bf16x8*)qp;
    qf[1] = *(const bf16x8*)(qp + 32);
  }

  f32x4 o[4] = {};
  float m = -1e30f, l = 0.f;

  const int srow = tid >> 2;            // staging row 0..63
  const int c16 = (tid & 3) * 16;       // staging col (elements)
  const int rb = srow * 128;            // row byte base in LDS tile
  const int sw = (srow & 7) << 4;       // XOR swizzle
  const bf16* kbase = kmat + (size_t)(b_ * 2048) * 1024 + h_ * 64;
  const bf16* vbase = vt + (size_t)(b_ * 16 + h_) * 64 * 2048;
  const bf16* kp0 = kbase + (size_t)srow * 1024 + c16;
  const bf16* vp0 = vbase + (size_t)srow * 2048 + c16;

  bf16x8 k0 = *(const bf16x8*)kp0;
  bf16x8 k1 = *(const bf16x8*)(kp0 + 8);
  bf16x8 v0 = *(const bf16x8*)vp0;
  bf16x8 v1 = *(const bf16x8*)(vp0 + 8);

  for (int s0 = 0; s0 <= qb; s0 += 64) {
    *(bf16x8*)((char*)Ks + ((rb + c16 * 2) ^ sw)) = k0;
    *(bf16x8*)((char*)Ks + ((rb + c16 * 2 + 16) ^ sw)) = k1;
    *(bf16x8*)((char*)Vs + ((rb + c16 * 2) ^ sw)) = v0;
    *(bf16x8*)((char*)Vs + ((rb + c16 * 2 + 16) ^ sw)) = v1;
    __syncthreads();
    if (s0 < qb) {  // prefetch next K/V tile into regs during compute
      const bf16* kp = kp0 + (size_t)(s0 + 64) * 1024;
      k0 = *(const bf16x8*)kp;
      k1 = *(const bf16x8*)(kp + 8);
      const bf16* vp = vp0 + (s0 + 64);
      v0 = *(const bf16x8*)vp;
      v1 = *(const bf16x8*)(vp + 8);
    }

    // S^T = K @ Q^T : lane holds S[q=qrow][s = s0 + 16n + 4g + r]
    f32x4 st[4];
#pragma unroll
    for (int n = 0; n < 4; ++n) {
      f32x4 z = {};
#pragma unroll
      for (int kk = 0; kk < 2; ++kk) {
        const int row = n * 16 + lr;
        bf16x8 ak = *(const bf16x8*)((char*)Ks +
            ((row * 128 + kk * 64 + g * 16) ^ ((lr & 7) << 4)));
        z = MFMA16(ak, qf[kk], z);
      }
      st[n] = z;
    }

    const bool needmask = (s0 == qb);
    float pm = -1e30f;
#pragma unroll
    for (int n = 0; n < 4; ++n)
#pragma unroll
      for (int r = 0; r < 4; ++r) {
        float sv = st[n][r] * 0.125f;  // 1/sqrt(64)
        if (needmask && (s0 + n * 16 + g * 4 + r > qrow)) sv = -1e30f;
        st[n][r] = sv;
        pm = fmaxf(pm, sv);
      }
    pm = fmaxf(pm, __shfl_xor(pm, 16));
    pm = fmaxf(pm, __shfl_xor(pm, 32));
    const float mn = fmaxf(m, pm);
    const float alpha = __expf(m - mn);
    m = mn;

    float rs = 0.f;
#pragma unroll
    for (int n = 0; n < 4; ++n) {
      bf16x4 pk;
#pragma unroll
      for (int r = 0; r < 4; ++r) {
        const float p = __expf(st[n][r] - mn);
        rs += p;
        pk[r] = (bf16)p;
      }
      *(bf16x4*)&Pq[w][lr][n * 16 + g * 4] = pk;  // P[q][s], s consecutive
    }
    rs += __shfl_xor(rs, 16);
    rs += __shfl_xor(rs, 32);
    l = l * alpha + rs;

    float av[4];
#pragma unroll
    for (int r = 0; r < 4; ++r) av[r] = __shfl(alpha, g * 4 + r);
#pragma unroll
    for (int n = 0; n < 4; ++n)
#pragma unroll
      for (int r = 0; r < 4; ++r) o[n][r] *= av[r];

    bf16x8 pa[2];
#pragma unroll
    for (int kk = 0; kk < 2; ++kk)
      pa[kk] = *(const bf16x8*)&Pq[w][lr][kk * 32 + g * 8];
#pragma unroll
    for (int n = 0; n < 4; ++n) {
      const int row = n * 16 + lr;
#pragma unroll
      for (int kk = 0; kk < 2; ++kk) {
        bf16x8 bv = *(const bf16x8*)((char*)Vs +
            ((row * 128 + kk * 64 + g * 16) ^ ((lr & 7) << 4)));
        o[n] = MFMA16(pa[kk], bv, o[n]);
      }
    }
    __syncthreads();
  }

  float lq[4];
#pragma unroll
  for (int r = 0; r < 4; ++r) lq[r] = __shfl(l, g * 4 + r);
#pragma unroll
  for (int r = 0; r < 4; ++r) {
    const float inv = 1.0f / lq[r];
#pragma unroll
    for (int n = 0; n < 4; ++n)
      ctx[(size_t)(b_ * 2048 + qb + w * 16 + g * 4 + r) * 1024 + h_ * 64 + n * 16 + lr] =
          (bf16)(o[n][r] * inv);
  }
}

// ---------------------------------------------------------------------------
extern "C" void kernel_launch(void* const* d_in, const int* in_sizes, int n_in,
                              void* d_out, int out_size, void* d_ws, size_t ws_size,
                              hipStream_t stream)
{
  (void)in_sizes; (void)n_in; (void)out_size; (void)ws_size;
  const float* x   = (const float*)d_in[0];
  const float* Wq  = (const float*)d_in[1];
  const float* bq  = (const float*)d_in[2];
  const float* Wk  = (const float*)d_in[3];
  const float* bk  = (const float*)d_in[4];
  const float* Wv  = (const float*)d_in[5];
  const float* bv  = (const float*)d_in[6];
  const float* Wo  = (const float*)d_in[7];
  const float* bo  = (const float*)d_in[8];
  const float* W1  = (const float*)d_in[9];
  const float* b1  = (const float*)d_in[10];
  const float* W2  = (const float*)d_in[11];
  const float* b2  = (const float*)d_in[12];
  const float* g1  = (const float*)d_in[13];
  const float* be1 = (const float*)d_in[14];
  const float* g2  = (const float*)d_in[15];
  const float* be2 = (const float*)d_in[16];
  float* out = (float*)d_out;

  char* ws = (char*)d_ws;
  const size_t MB = 1024 * 1024;
  bf16* wqkv_t = (bf16*)(ws + 0 * MB);  // [3072][1024]: wq|wk|wv contiguous
  bf16* wq_t = (bf16*)(ws + 0 * MB);
  bf16* wk_t = (bf16*)(ws + 2 * MB);
  bf16* wv_t = (bf16*)(ws + 4 * MB);
  bf16* wo_t = (bf16*)(ws + 6 * MB);
  bf16* w1_t = (bf16*)(ws + 8 * MB);   // [4096][1024]
  bf16* w2_t = (bf16*)(ws + 16 * MB);  // [1024][4096]
  bf16* h1   = (bf16*)(ws + 24 * MB);  // [4096][1024]
  bf16* qbuf = (bf16*)(ws + 32 * MB);  // [4096][1024]
  bf16* kbuf = (bf16*)(ws + 40 * MB);  // [4096][1024]
  bf16* vtb  = (bf16*)(ws + 48 * MB);  // [2][16][64][2048]
  bf16* ctx  = (bf16*)(ws + 56 * MB);  // [4096][1024]
  bf16* h2   = (bf16*)(ws + 64 * MB);  // [4096][1024]
  bf16* ff1  = (bf16*)(ws + 24 * MB);  // [4096][4096], overlays h1/q/k/vtb (dead)

  const dim3 tb(32, 8);
  transpose_cvt_kernel<<<dim3(32, 32), tb, 0, stream>>>(Wq, wq_t, 1024, 1024);
  transpose_cvt_kernel<<<dim3(32, 32), tb, 0, stream>>>(Wk, wk_t, 1024, 1024);
  transpose_cvt_kernel<<<dim3(32, 32), tb, 0, stream>>>(Wv, wv_t, 1024, 1024);
  transpose_cvt_kernel<<<dim3(32, 32), tb, 0, stream>>>(Wo, wo_t, 1024, 1024);
  transpose_cvt_kernel<<<dim3(128, 32), tb, 0, stream>>>(W1, w1_t, 1024, 4096);
  transpose_cvt_kernel<<<dim3(32, 128), tb, 0, stream>>>(W2, w2_t, 4096, 1024);

  ln_kernel<<<4096, 256, 0, stream>>>(x, g1, be1, h1);

  // fused QKV: [4096,1024] @ [1024,3072] -> q,k,v(transposed)
  gemm_bt<128, 32, 4><<<dim3(24, 32), 256, 0, stream>>>(
      h1, wqkv_t, bq, bk, bv, nullptr, qbuf, kbuf, vtb, nullptr, 4096, 3072, 1024);

  attn_kernel<<<dim3(32, 32), 256, 0, stream>>>(qbuf, kbuf, vtb, ctx);

  // x2 = x + ctx@Wo + bo -> d_out (fp32)
  gemm_bt<64, 64, 2><<<dim3(16, 32), 256, 0, stream>>>(
      ctx, wo_t, bo, nullptr, nullptr, x, nullptr, nullptr, nullptr, out, 4096, 1024, 1024);

  ln_kernel<<<4096, 256, 0, stream>>>(out, g2, be2, h2);

  gemm_bt<128, 32, 1><<<dim3(32, 32), 256, 0, stream>>>(
      h2, w1_t, b1, nullptr, nullptr, nullptr, ff1, nullptr, nullptr, nullptr, 4096, 4096, 1024);

  // out = x2 + ff1@W2 + b2 (in-place read+write of d_out, 1 thread/element)
  gemm_bt<64, 64, 2><<<dim3(16, 32), 256, 0, stream>>>(
      ff1, w2_t, b2, nullptr, nullptr, out, nullptr, nullptr, nullptr, out, 4096, 1024, 4096);
}

// Round 6
// 225.506 us; speedup vs baseline: 1.2406x; 1.0484x over previous
//
#include <hip/hip_runtime.h>

typedef __bf16 bf16;
typedef __attribute__((ext_vector_type(8))) __bf16 bf16x8;
typedef __attribute__((ext_vector_type(4))) __bf16 bf16x4;
typedef __attribute__((ext_vector_type(4))) float f32x4;

#define MFMA16(A, B, C) __builtin_amdgcn_mfma_f32_16x16x32_bf16(A, B, C, 0, 0, 0)

// async global->LDS, 16B per lane: dest = (wave-uniform base) + lane*16
#define GLOAD16(gp, lp)                                          \
  __builtin_amdgcn_global_load_lds(                              \
      (const __attribute__((address_space(1))) void*)(gp),       \
      (__attribute__((address_space(3))) void*)(lp), 16, 0, 0)

// 2^x (v_exp_f32 computes 2^S0)
__device__ __forceinline__ float fexp2(float x) {
#if __has_builtin(__builtin_amdgcn_exp2f)
  return __builtin_amdgcn_exp2f(x);
#else
  float r;
  asm("v_exp_f32 %0, %1" : "=v"(r) : "v"(x));
  return r;
#endif
}

// Q pre-scale: scores = (q.k)/sqrt(64) in log2 units for exp2-softmax
#define QSCL 0.18033688011112042f  // 0.125 * log2(e)

// ---------------------------------------------------------------------------
// Transpose + fp32->bf16 convert: out[N][K] = (bf16) in[K][N]
// ---------------------------------------------------------------------------
__global__ __launch_bounds__(256) void transpose_cvt_kernel(
    const float* __restrict__ in, bf16* __restrict__ out, int K, int N)
{
  __shared__ float tile[32][33];
  const int kt = blockIdx.y * 32;
  const int nt = blockIdx.x * 32;
  const int tx = threadIdx.x, ty = threadIdx.y;
#pragma unroll
  for (int j = 0; j < 4; ++j)
    tile[ty + j * 8][tx] = in[(size_t)(kt + ty + j * 8) * N + nt + tx];
  __syncthreads();
#pragma unroll
  for (int j = 0; j < 4; ++j)
    out[(size_t)(nt + ty + j * 8) * K + kt + tx] = (bf16)tile[tx][ty + j * 8];
}

// ---------------------------------------------------------------------------
// LayerNorm (eps=1e-3), fp32 in -> bf16 out. One block per row of 1024.
// ---------------------------------------------------------------------------
__global__ __launch_bounds__(256) void ln_kernel(
    const float* __restrict__ in, const float* __restrict__ gamma,
    const float* __restrict__ beta, bf16* __restrict__ out)
{
  const int row = blockIdx.x;
  const int t = threadIdx.x;
  const float4 v = ((const float4*)(in + (size_t)row * 1024))[t];
  float s = v.x + v.y + v.z + v.w;
  float sq = v.x * v.x + v.y * v.y + v.z * v.z + v.w * v.w;
#pragma unroll
  for (int m = 1; m < 64; m <<= 1) {
    s += __shfl_xor(s, m);
    sq += __shfl_xor(sq, m);
  }
  __shared__ float ssum[4], ssq[4];
  const int w = t >> 6;
  if ((t & 63) == 0) { ssum[w] = s; ssq[w] = sq; }
  __syncthreads();
  s = ssum[0] + ssum[1] + ssum[2] + ssum[3];
  sq = ssq[0] + ssq[1] + ssq[2] + ssq[3];
  const float mu = s * (1.0f / 1024.0f);
  const float var = sq * (1.0f / 1024.0f) - mu * mu;
  const float rs = rsqrtf(var + 1e-3f);
  const float4 g = ((const float4*)gamma)[t];
  const float4 b = ((const float4*)beta)[t];
  bf16x4 o;
  o[0] = (bf16)((v.x - mu) * rs * g.x + b.x);
  o[1] = (bf16)((v.y - mu) * rs * g.y + b.y);
  o[2] = (bf16)((v.z - mu) * rs * g.z + b.z);
  o[3] = (bf16)((v.w - mu) * rs * g.w + b.w);
  *(bf16x4*)(out + (size_t)row * 1024 + t * 4) = o;
}

// ---------------------------------------------------------------------------
// GEMM: C[M,N] = epilogue(A[M,K] @ Bt[N,K]^T + bias)
// T3+T4 pipeline: 3 LDS buffers, prefetch distance 2 via global_load_lds(16B),
// counted s_waitcnt vmcnt(S) (never 0 in main loop) + raw s_barrier.
// T2 swizzle (both-sides): linear LDS dest, source chunk = slot^(row&SMASK),
// ds_read col slot = chunk^(row&SMASK)  (XOR involution, rule #21).
// T5 setprio(1/0) around the MFMA cluster.
// EPI 1: bf16 relu -> out0
// EPI 2: f32 out = acc + bias0 + resid -> outf
// EPI 4: fused QKV: col<1024 -> out0((acc+bias0)*QSCL, pre-scaled for attn);
//        <2048 -> out1(+bias1); else V per-head transposed [b][h][d][t]
// ---------------------------------------------------------------------------
template <int BN, int BK, int EPI>
__global__ __launch_bounds__(256) void gemm_bt(
    const bf16* __restrict__ A, const bf16* __restrict__ Bt,
    const float* __restrict__ bias0, const float* __restrict__ bias1,
    const float* __restrict__ bias2, const float* __restrict__ resid,
    bf16* __restrict__ out0, bf16* __restrict__ out1, bf16* __restrict__ out2,
    float* __restrict__ outf, int M, int N, int K)
{
  constexpr int WN = BN / 2;        // wave tile cols
  constexpr int NJ = WN / 16;       // col fragments per wave
  constexpr int KK = BK / 32;       // mfma k-substeps per K-step
  constexpr int NSLOT = BK / 8;     // 16B slots per LDS row
  constexpr int SMASK = NSLOT - 1;
  constexpr int RPL = 512 / BK;     // rows covered per gload16
  constexpr int ALOADS = 128 / (4 * RPL);
  constexpr int BLOADS = BN / (4 * RPL);
  constexpr int S = ALOADS + BLOADS;  // gloads per wave per stage

  __shared__ bf16 As[3][128 * BK];
  __shared__ bf16 Bs[3][BN * BK];
  const int tid = threadIdx.x;
  const int lane = tid & 63, w = tid >> 6;
  const int wr = w >> 1, wc = w & 1;
  const int g = lane >> 4, lr = lane & 15;
  const int brow = blockIdx.y * 128, bcol = blockIdx.x * BN;

  f32x4 acc[4][NJ] = {};

  const int lrow = lane / NSLOT;               // row within a gload group
  const int slot = lane & SMASK;               // this lane's linear LDS slot
  const int lcol = (slot ^ (lrow & SMASK)) * 8;  // swizzled source chunk

  auto stage = [&](int buf, int k0) {
#pragma unroll
    for (int j = 0; j < ALOADS; ++j) {
      const int row0 = w * 32 + j * RPL;
      GLOAD16(A + (size_t)(brow + row0 + lrow) * K + k0 + lcol,
              &As[buf][row0 * BK]);
    }
#pragma unroll
    for (int j = 0; j < BLOADS; ++j) {
      const int row0 = w * (BN / 4) + j * RPL;
      GLOAD16(Bt + (size_t)(bcol + row0 + lrow) * K + k0 + lcol,
              &Bs[buf][row0 * BK]);
    }
  };

  const int nk = K / BK;
  stage(0, 0);
  stage(1, BK);
  int cur = 0;
  for (int t = 0; t < nk; ++t) {
    // Wait for tile t's stage (issued at t-2); keep tile t+1's S loads in
    // flight (counted vmcnt, never 0 mid-loop). Last iter: drain.
    if (t + 1 < nk) {
      if constexpr (S == 3)
        asm volatile("s_waitcnt vmcnt(3)" ::: "memory");
      else if constexpr (S == 4)
        asm volatile("s_waitcnt vmcnt(4)" ::: "memory");
      else
        asm volatile("s_waitcnt vmcnt(6)" ::: "memory");
    } else {
      asm volatile("s_waitcnt vmcnt(0)" ::: "memory");
    }
    __builtin_amdgcn_s_barrier();
    __builtin_amdgcn_sched_barrier(0);  // pin reads/stage below the barrier

    bf16x8 afr[4][KK], bfr[NJ][KK];
#pragma unroll
    for (int i = 0; i < 4; ++i)
#pragma unroll
      for (int kk = 0; kk < KK; ++kk)
        afr[i][kk] = *(const bf16x8*)&As[cur][(wr * 64 + i * 16 + lr) * BK +
                                             (((kk * 4 + g) ^ (lr & SMASK)) * 8)];
#pragma unroll
    for (int j = 0; j < NJ; ++j)
#pragma unroll
      for (int kk = 0; kk < KK; ++kk)
        bfr[j][kk] = *(const bf16x8*)&Bs[cur][(wc * WN + j * 16 + lr) * BK +
                                             (((kk * 4 + g) ^ (lr & SMASK)) * 8)];

    if (t + 2 < nk) {  // prefetch tile t+2 into the buffer freed at t-1
      int nb = cur + 2;
      if (nb >= 3) nb -= 3;
      stage(nb, (t + 2) * BK);
    }

    __builtin_amdgcn_s_setprio(1);
#pragma unroll
    for (int kk = 0; kk < KK; ++kk)
#pragma unroll
      for (int i = 0; i < 4; ++i)
#pragma unroll
        for (int j = 0; j < NJ; ++j)
          acc[i][j] = MFMA16(afr[i][kk], bfr[j][kk], acc[i][j]);
    __builtin_amdgcn_s_setprio(0);

    ++cur;
    if (cur == 3) cur = 0;
  }

#pragma unroll
  for (int i = 0; i < 4; ++i) {
#pragma unroll
    for (int j = 0; j < NJ; ++j) {
      const int r0 = brow + wr * 64 + i * 16 + g * 4;
      const int c = bcol + wc * WN + j * 16 + lr;
      if constexpr (EPI == 1) {
        const float bv = bias0[c];
#pragma unroll
        for (int rr = 0; rr < 4; ++rr)
          out0[(size_t)(r0 + rr) * N + c] = (bf16)fmaxf(acc[i][j][rr] + bv, 0.0f);
      } else if constexpr (EPI == 2) {
        const float bv = bias0[c];
#pragma unroll
        for (int rr = 0; rr < 4; ++rr) {
          const size_t idx = (size_t)(r0 + rr) * N + c;
          outf[idx] = acc[i][j][rr] + bv + resid[idx];
        }
      } else {  // EPI 4: fused QKV
        const int sub = c >> 10;  // block-uniform (128-col tiles)
        const int c1 = c & 1023;
        if (sub == 0) {  // Q, pre-scaled into log2-softmax units
          const float bv = bias0[c1];
#pragma unroll
          for (int rr = 0; rr < 4; ++rr)
            out0[(size_t)(r0 + rr) * 1024 + c1] =
                (bf16)((acc[i][j][rr] + bv) * QSCL);
        } else if (sub == 1) {
          const float bv = bias1[c1];
#pragma unroll
          for (int rr = 0; rr < 4; ++rr)
            out1[(size_t)(r0 + rr) * 1024 + c1] = (bf16)(acc[i][j][rr] + bv);
        } else {
          const float bv = bias2[c1];
          const int bb = r0 >> 11, t0 = r0 & 2047;
          const int hh = c1 >> 6, dd = c1 & 63;
          bf16x4 pk;
#pragma unroll
          for (int rr = 0; rr < 4; ++rr) pk[rr] = (bf16)(acc[i][j][rr] + bv);
          *(bf16x4*)(out2 + ((size_t)((bb * 16 + hh) * 64 + dd)) * 2048 + t0) = pk;
        }
      }
    }
  }
}

// ---------------------------------------------------------------------------
// Causal flash attention, S^T formulation: per lane one q-row (q = lane&15).
// q is pre-scaled by 0.125*log2(e) -> scores in log2 units, softmax via exp2.
// Complementary-pair qt mapping: CU's 4 blocks (bid stride 512 pairs) sum to
// exactly 66 s-tiles -> balanced CU load. T13 defer-max (THR=8, log2 units).
// q,k: [4096][1024] bf16 ; vt: [b][h][64 d][2048 t] bf16 ; ctx: [4096][1024]
// ---------------------------------------------------------------------------
__global__ __launch_bounds__(256) void attn_kernel(
    const bf16* __restrict__ q, const bf16* __restrict__ kmat,
    const bf16* __restrict__ vt, bf16* __restrict__ ctx)
{
  __shared__ bf16 Ks[64 * 64];
  __shared__ bf16 Vs[64 * 64];
  __shared__ bf16 Pq[4][16][88];  // per-wave P [q][s], stride 88
  const int bx = blockIdx.x, by = blockIdx.y;
  const int qt = (by & 16) ? (31 - ((bx + by - 16) & 31)) : ((bx + by) & 31);
  const int b_ = by >> 4, h_ = by & 15;
  const int qb = qt * 64;
  const int tid = threadIdx.x;
  const int lane = tid & 63, w = tid >> 6;
  const int g = lane >> 4, lr = lane & 15;
  const int qrow = qb + w * 16 + lr;  // this lane's q row (S^T layout)

  bf16x8 qf[2];
  {
    const bf16* qp = q + (size_t)(b_ * 2048 + qrow) * 1024 + h_ * 64 + g * 8;
    qf[0] = *(const bf16x8*)qp;
    qf[1] = *(const bf16x8*)(qp + 32);
  }

  f32x4 o[4] = {};
  float m = -1e30f, l = 0.f;

  const int srow = tid >> 2;            // staging row 0..63
  const int c16 = (tid & 3) * 16;       // staging col (elements)
  const int rb = srow * 128;            // row byte base in LDS tile
  const int sw = (srow & 7) << 4;       // XOR swizzle
  const bf16* kbase = kmat + (size_t)(b_ * 2048) * 1024 + h_ * 64;
  const bf16* vbase = vt + (size_t)(b_ * 16 + h_) * 64 * 2048;
  const bf16* kp0 = kbase + (size_t)srow * 1024 + c16;
  const bf16* vp0 = vbase + (size_t)srow * 2048 + c16;

  bf16x8 k0 = *(const bf16x8*)kp0;
  bf16x8 k1 = *(const bf16x8*)(kp0 + 8);
  bf16x8 v0 = *(const bf16x8*)vp0;
  bf16x8 v1 = *(const bf16x8*)(vp0 + 8);

  for (int s0 = 0; s0 <= qb; s0 += 64) {
    *(bf16x8*)((char*)Ks + ((rb + c16 * 2) ^ sw)) = k0;
    *(bf16x8*)((char*)Ks + ((rb + c16 * 2 + 16) ^ sw)) = k1;
    *(bf16x8*)((char*)Vs + ((rb + c16 * 2) ^ sw)) = v0;
    *(bf16x8*)((char*)Vs + ((rb + c16 * 2 + 16) ^ sw)) = v1;
    __syncthreads();
    if (s0 < qb) {  // prefetch next K/V tile into regs during compute
      const bf16* kp = kp0 + (size_t)(s0 + 64) * 1024;
      k0 = *(const bf16x8*)kp;
      k1 = *(const bf16x8*)(kp + 8);
      const bf16* vp = vp0 + (s0 + 64);
      v0 = *(const bf16x8*)vp;
      v1 = *(const bf16x8*)(vp + 8);
    }

    // S^T = K @ Q^T : lane holds S[q=qrow][s = s0 + 16n + 4g + r] (log2 units)
    f32x4 st[4];
#pragma unroll
    for (int n = 0; n < 4; ++n) {
      f32x4 z = {};
#pragma unroll
      for (int kk = 0; kk < 2; ++kk) {
        const int row = n * 16 + lr;
        bf16x8 ak = *(const bf16x8*)((char*)Ks +
            ((row * 128 + kk * 64 + g * 16) ^ ((lr & 7) << 4)));
        z = MFMA16(ak, qf[kk], z);
      }
      st[n] = z;
    }

    if (s0 == qb) {  // causal mask on the diagonal tile
#pragma unroll
      for (int n = 0; n < 4; ++n)
#pragma unroll
        for (int r = 0; r < 4; ++r)
          if (s0 + n * 16 + g * 4 + r > qrow) st[n][r] = -1e30f;
    }

    float pm = -1e30f;
#pragma unroll
    for (int n = 0; n < 4; ++n)
#pragma unroll
      for (int r = 0; r < 4; ++r) pm = fmaxf(pm, st[n][r]);
    pm = fmaxf(pm, __shfl_xor(pm, 16));
    pm = fmaxf(pm, __shfl_xor(pm, 32));

    // T13 defer-max: only rescale when some row's max grew past m+8
    if (__any(pm > m + 8.0f)) {
      const float mn = fmaxf(m, pm);
      const float alpha = fexp2(m - mn);
      m = mn;
      l *= alpha;
      float av[4];
#pragma unroll
      for (int r = 0; r < 4; ++r) av[r] = __shfl(alpha, g * 4 + r);
#pragma unroll
      for (int n = 0; n < 4; ++n)
#pragma unroll
        for (int r = 0; r < 4; ++r) o[n][r] *= av[r];
    }

    float rs = 0.f;
#pragma unroll
    for (int n = 0; n < 4; ++n) {
      bf16x4 pk;
#pragma unroll
      for (int r = 0; r < 4; ++r) {
        const float p = fexp2(st[n][r] - m);  // bounded by 2^8
        rs += p;
        pk[r] = (bf16)p;
      }
      *(bf16x4*)&Pq[w][lr][n * 16 + g * 4] = pk;  // P[q][s], s consecutive
    }
    rs += __shfl_xor(rs, 16);
    rs += __shfl_xor(rs, 32);
    l += rs;

    bf16x8 pa[2];
#pragma unroll
    for (int kk = 0; kk < 2; ++kk)
      pa[kk] = *(const bf16x8*)&Pq[w][lr][kk * 32 + g * 8];
#pragma unroll
    for (int n = 0; n < 4; ++n) {
      const int row = n * 16 + lr;
#pragma unroll
      for (int kk = 0; kk < 2; ++kk) {
        bf16x8 bv = *(const bf16x8*)((char*)Vs +
            ((row * 128 + kk * 64 + g * 16) ^ ((lr & 7) << 4)));
        o[n] = MFMA16(pa[kk], bv, o[n]);
      }
    }
    __syncthreads();
  }

  float lq[4];
#pragma unroll
  for (int r = 0; r < 4; ++r) lq[r] = __shfl(l, g * 4 + r);
#pragma unroll
  for (int r = 0; r < 4; ++r) {
    const float inv = 1.0f / lq[r];
#pragma unroll
    for (int n = 0; n < 4; ++n)
      ctx[(size_t)(b_ * 2048 + qb + w * 16 + g * 4 + r) * 1024 + h_ * 64 + n * 16 + lr] =
          (bf16)(o[n][r] * inv);
  }
}

// ---------------------------------------------------------------------------
extern "C" void kernel_launch(void* const* d_in, const int* in_sizes, int n_in,
                              void* d_out, int out_size, void* d_ws, size_t ws_size,
                              hipStream_t stream)
{
  (void)in_sizes; (void)n_in; (void)out_size; (void)ws_size;
  const float* x   = (const float*)d_in[0];
  const float* Wq  = (const float*)d_in[1];
  const float* bq  = (const float*)d_in[2];
  const float* Wk  = (const float*)d_in[3];
  const float* bk  = (const float*)d_in[4];
  const float* Wv  = (const float*)d_in[5];
  const float* bv  = (const float*)d_in[6];
  const float* Wo  = (const float*)d_in[7];
  const float* bo  = (const float*)d_in[8];
  const float* W1  = (const float*)d_in[9];
  const float* b1  = (const float*)d_in[10];
  const float* W2  = (const float*)d_in[11];
  const float* b2  = (const float*)d_in[12];
  const float* g1  = (const float*)d_in[13];
  const float* be1 = (const float*)d_in[14];
  const float* g2  = (const float*)d_in[15];
  const float* be2 = (const float*)d_in[16];
  float* out = (float*)d_out;

  char* ws = (char*)d_ws;
  const size_t MB = 1024 * 1024;
  bf16* wqkv_t = (bf16*)(ws + 0 * MB);  // [3072][1024]: wq|wk|wv contiguous
  bf16* wq_t = (bf16*)(ws + 0 * MB);
  bf16* wk_t = (bf16*)(ws + 2 * MB);
  bf16* wv_t = (bf16*)(ws + 4 * MB);
  bf16* wo_t = (bf16*)(ws + 6 * MB);
  bf16* w1_t = (bf16*)(ws + 8 * MB);   // [4096][1024]
  bf16* w2_t = (bf16*)(ws + 16 * MB);  // [1024][4096]
  bf16* h1   = (bf16*)(ws + 24 * MB);  // [4096][1024]
  bf16* qbuf = (bf16*)(ws + 32 * MB);  // [4096][1024]
  bf16* kbuf = (bf16*)(ws + 40 * MB);  // [4096][1024]
  bf16* vtb  = (bf16*)(ws + 48 * MB);  // [2][16][64][2048]
  bf16* ctx  = (bf16*)(ws + 56 * MB);  // [4096][1024]
  bf16* h2   = (bf16*)(ws + 64 * MB);  // [4096][1024]
  bf16* ff1  = (bf16*)(ws + 24 * MB);  // [4096][4096], overlays h1/q/k/vtb (dead)

  const dim3 tb(32, 8);
  transpose_cvt_kernel<<<dim3(32, 32), tb, 0, stream>>>(Wq, wq_t, 1024, 1024);
  transpose_cvt_kernel<<<dim3(32, 32), tb, 0, stream>>>(Wk, wk_t, 1024, 1024);
  transpose_cvt_kernel<<<dim3(32, 32), tb, 0, stream>>>(Wv, wv_t, 1024, 1024);
  transpose_cvt_kernel<<<dim3(32, 32), tb, 0, stream>>>(Wo, wo_t, 1024, 1024);
  transpose_cvt_kernel<<<dim3(128, 32), tb, 0, stream>>>(W1, w1_t, 1024, 4096);
  transpose_cvt_kernel<<<dim3(32, 128), tb, 0, stream>>>(W2, w2_t, 4096, 1024);

  ln_kernel<<<4096, 256, 0, stream>>>(x, g1, be1, h1);

  // fused QKV: [4096,1024] @ [1024,3072] -> q(prescaled),k,v(transposed)
  gemm_bt<128, 32, 4><<<dim3(24, 32), 256, 0, stream>>>(
      h1, wqkv_t, bq, bk, bv, nullptr, qbuf, kbuf, vtb, nullptr, 4096, 3072, 1024);

  attn_kernel<<<dim3(32, 32), 256, 0, stream>>>(qbuf, kbuf, vtb, ctx);

  // x2 = x + ctx@Wo + bo -> d_out (fp32)
  gemm_bt<64, 64, 2><<<dim3(16, 32), 256, 0, stream>>>(
      ctx, wo_t, bo, nullptr, nullptr, x, nullptr, nullptr, nullptr, out, 4096, 1024, 1024);

  ln_kernel<<<4096, 256, 0, stream>>>(out, g2, be2, h2);

  gemm_bt<128, 32, 1><<<dim3(32, 32), 256, 0, stream>>>(
      h2, w1_t, b1, nullptr, nullptr, nullptr, ff1, nullptr, nullptr, nullptr, 4096, 4096, 1024);

  // out = x2 + ff1@W2 + b2 (in-place read+write of d_out, 1 thread/element)
  gemm_bt<64, 64, 2><<<dim3(16, 32), 256, 0, stream>>>(
      ff1, w2_t, b2, nullptr, nullptr, out, nullptr, nullptr, nullptr, out, 4096, 1024, 4096);
}